// Round 5
// baseline (35182.367 us; speedup 1.0000x reference)
//
#include <hip/hip_runtime.h>
#include <math.h>

#define BSZ 32
#define TT  32
#define XD  128
#define HD  512
#define VT  2048
#define WD  64
#define RDM 4
#define NDM 1024
#define ET  463
#define GKS 8
#define VKS 16
#define NB  256
#define TPB 512

typedef unsigned long long ull;

__device__ __forceinline__ float sigf(float x){ return 1.f/(1.f+expf(-x)); }
__device__ __forceinline__ float logsigf(float x){
    return (x >= 0.f) ? -log1pf(expf(-x)) : x - log1pf(expf(x));
}

union SMem {
    float getile[64*36];        // lstm gemm staging (9.2KB)
    float gvtile[128*36];       // gemv staging (18.4KB)
    struct {
        float buf[464];
        float ers[64];
        float wred[8];
        float nrm4[4];
        ull   keys[1024];
        float pa[1024];
        float pb[1024];
        float red[1024];
        float p4[4096];
    } mm;                       // ~39KB
    float rvf[32*256];          // ywr staging (32KB)
};

// block reductions over 512 threads (8 waves)
__device__ __forceinline__ float bsum8(float v, float* wred){
    #pragma unroll
    for (int o = 32; o > 0; o >>= 1) v += __shfl_xor(v, o);
    int lane = threadIdx.x & 63, wid = threadIdx.x >> 6;
    if (lane == 0) wred[wid] = v;
    __syncthreads();
    if (wid == 0){
        float s = (lane < 8) ? wred[lane] : 0.f;
        #pragma unroll
        for (int o = 4; o > 0; o >>= 1) s += __shfl_xor(s, o);
        if (lane == 0) wred[0] = s;
    }
    __syncthreads();
    float r = wred[0];
    __syncthreads();
    return r;
}
__device__ __forceinline__ float bmax8(float v, float* wred){
    #pragma unroll
    for (int o = 32; o > 0; o >>= 1) v = fmaxf(v, __shfl_xor(v, o));
    int lane = threadIdx.x & 63, wid = threadIdx.x >> 6;
    if (lane == 0) wred[wid] = v;
    __syncthreads();
    if (wid == 0){
        float s = (lane < 8) ? wred[lane] : -3.4e38f;
        #pragma unroll
        for (int o = 4; o > 0; o >>= 1) s = fmaxf(s, __shfl_xor(s, o));
        if (lane == 0) wred[0] = s;
    }
    __syncthreads();
    float r = wred[0];
    __syncthreads();
    return r;
}

// device-wide epoch barrier: all NB blocks co-resident (1 block/CU).
__device__ __forceinline__ void gsync(unsigned* cnt, unsigned target){
    __syncthreads();
    if (threadIdx.x == 0){
        __threadfence();                 // release all prior writes
        atomicAdd(cnt, 1u);              // device-scope
        while (__hip_atomic_load(cnt, __ATOMIC_ACQUIRE, __HIP_MEMORY_SCOPE_AGENT) < target)
            __builtin_amdgcn_s_sleep(1);
        __threadfence();                 // acquire
    }
    __syncthreads();
}

// LSTM gemm phase: 256 blocks = (16 jc, 2 d, 8 ks); 512 thr: 4j x 2b acc
__device__ __forceinline__ void lstm_gemm_phase(
    int bid, int tid, float* tile,
    const float* __restrict__ srcA, int stA, int cA,
    const float* __restrict__ srcB, int stB, int cB,
    const float* __restrict__ hsrc,
    const float* __restrict__ Wih, int Kih,
    const float* __restrict__ Whh,
    float* __restrict__ gpart)
{
    const int jc = bid & 15, d = (bid >> 4) & 1, ks = bid >> 5;
    const int jg = tid & 31, bg = tid >> 5;
    const int j0 = jc*128 + jg*4, b0 = bg*2;
    const int cAB = cA + cB, nct = cAB + 8;
    const int per = (nct + 7) >> 3;
    int c0 = ks*per, c1 = min(nct, c0 + per);
    float acc[4][2] = {{0}};
    for (int c = c0; c < c1; ++c){
        const float* src; int stride, kb; const float* Wb; int Kw, kcol;
        if (c < cA){ src = srcA; stride = stA; kb = c*64; Wb = Wih + (size_t)d*2048*Kih; Kw = Kih; kcol = c*64; }
        else if (c < cAB){ src = srcB; stride = stB; kb = (c - cA)*64; Wb = Wih + (size_t)d*2048*Kih; Kw = Kih; kcol = c*64; }
        else { src = hsrc + d*(BSZ*HD); stride = HD; kb = (c - cAB)*64; Wb = Whh + (size_t)d*2048*HD; Kw = HD; kcol = kb; }
        #pragma unroll
        for (int i = 0; i < 4; ++i){
            int idx = i*TPB + tid; int kk = idx & 63, b = idx >> 6;
            tile[kk*36 + b] = src[b*stride + kb + kk];
        }
        __syncthreads();
        const float* wp0 = Wb + (size_t)(j0+0)*Kw + kcol;
        const float* wp1 = Wb + (size_t)(j0+1)*Kw + kcol;
        const float* wp2 = Wb + (size_t)(j0+2)*Kw + kcol;
        const float* wp3 = Wb + (size_t)(j0+3)*Kw + kcol;
        for (int kk = 0; kk < 64; kk += 4){
            float2 a0 = *(const float2*)&tile[(kk+0)*36 + b0];
            float2 a1 = *(const float2*)&tile[(kk+1)*36 + b0];
            float2 a2 = *(const float2*)&tile[(kk+2)*36 + b0];
            float2 a3 = *(const float2*)&tile[(kk+3)*36 + b0];
            float4 w;
            #define ACC1(JJ, WP) \
                w = *(const float4*)(WP + kk); \
                acc[JJ][0] += a0.x*w.x + a1.x*w.y + a2.x*w.z + a3.x*w.w; \
                acc[JJ][1] += a0.y*w.x + a1.y*w.y + a2.y*w.z + a3.y*w.w;
            ACC1(0, wp0) ACC1(1, wp1) ACC1(2, wp2) ACC1(3, wp3)
            #undef ACC1
        }
        __syncthreads();
    }
    #pragma unroll
    for (int bb = 0; bb < 2; ++bb){
        float4 o = make_float4(acc[0][bb], acc[1][bb], acc[2][bb], acc[3][bb]);
        *(float4*)&gpart[((size_t)(d*GKS + ks)*BSZ + (b0+bb))*2048 + j0] = o;
    }
}

// gates: needs exactly 64 blocks x 512 threads (2 dirs x 32 b x 512 u)
__device__ __forceinline__ void gates_phase(
    int bid, int tid,
    const float* __restrict__ gpart,
    const float* __restrict__ bih, const float* __restrict__ bhh,
    float* __restrict__ cstate, float* __restrict__ hstate,
    float* __restrict__ flat, float* __restrict__ lout, int l)
{
    int idx = bid*TPB + tid;
    int u = idx & 511, b = (idx >> 9) & 31, d = idx >> 14;
    int cell = 2*l + d;
    float g[4];
    #pragma unroll
    for (int xg = 0; xg < 4; ++xg){
        int j = xg*512 + u;
        float s = bih[d*2048 + j] + bhh[d*2048 + j];
        #pragma unroll
        for (int ks = 0; ks < GKS; ++ks)
            s += gpart[((size_t)(d*GKS + ks)*BSZ + b)*2048 + j];
        g[xg] = s;
    }
    float ig = sigf(g[0]), fg = sigf(g[1]), og = sigf(g[3]);
    float gg = tanhf(g[2]);
    int ci = (cell*BSZ + b)*HD + u;
    float c2 = fg*cstate[ci] + ig*gg;
    cstate[ci] = c2;
    float h = og*tanhf(c2);
    hstate[ci] = h;
    flat[b*2048 + cell*HD + u] = h;
    if (lout) lout[b*1024 + d*HD + u] = h;
}

__global__ __launch_bounds__(TPB) void dnc_persist(
    const float* __restrict__ x, const float* __restrict__ Wy,
    const float* __restrict__ WE, const float* __restrict__ Wr,
    const float* __restrict__ Wih0, const float* __restrict__ Whh0,
    const float* __restrict__ bih0, const float* __restrict__ bhh0,
    const float* __restrict__ Wih1, const float* __restrict__ Whh1,
    const float* __restrict__ bih1, const float* __restrict__ bhh1,
    unsigned* bar,
    float* hstate, float* cstate, float* ubuf, float* lww, float* lrw, float* lrv,
    float* M, float* xbn, float* lin1, float* gpart, float* flat,
    float* vtp, float* ep, float* yt_vt, float* out)
{
    const int bid = blockIdx.x, tid = threadIdx.x;
    unsigned epoch = 0;
    __shared__ SMem sm;

    // ---- batchnorm for all timesteps ----
    if (bid < TT && tid < XD){
        int t = bid, f = tid;
        float vals[BSZ]; float s = 0.f;
        #pragma unroll
        for (int b = 0; b < BSZ; ++b){ vals[b] = x[(b*TT + t)*XD + f]; s += vals[b]; }
        float mean = s * (1.f/BSZ);
        float ss = 0.f;
        #pragma unroll
        for (int b = 0; b < BSZ; ++b){ float d = vals[b] - mean; ss += d*d; }
        float inv = 1.f / sqrtf(ss*(1.f/BSZ) + 1e-5f);
        #pragma unroll
        for (int b = 0; b < BSZ; ++b) xbn[(t*BSZ + b)*XD + f] = (vals[b] - mean)*inv;
    }
    gsync(bar, (++epoch)*NB);

    for (int t = 0; t < TT; ++t){
        // ---- phase 1: LSTM layer0 gemm ----
        lstm_gemm_phase(bid, tid, sm.getile,
                        xbn + (size_t)t*BSZ*XD, XD, 2, lrv, 256, 4,
                        hstate, Wih0, 384, Whh0, gpart);
        gsync(bar, (++epoch)*NB);
        // ---- phase 2: gates layer0 (blocks 0..63 only!) ----
        if (bid < 64)
            gates_phase(bid, tid, gpart, bih0, bhh0, cstate, hstate, flat, lin1, 0);
        gsync(bar, (++epoch)*NB);
        // ---- phase 3: LSTM layer1 gemm ----
        lstm_gemm_phase(bid, tid, sm.getile,
                        lin1, 1024, 16, nullptr, 0, 0,
                        hstate + 2*BSZ*HD, Wih1, 1024, Whh1, gpart);
        gsync(bar, (++epoch)*NB);
        // ---- phase 4: gates layer1 (blocks 0..63 only!) ----
        if (bid < 64)
            gates_phase(bid, tid, gpart, bih1, bhh1, cstate, hstate, flat, nullptr, 1);
        gsync(bar, (++epoch)*NB);
        // ---- phase 5: gemv (Wy + WE), unit loop over (mbi,ksi) ----
        for (int unit = bid; unit < 20*16; unit += NB){
            int mbi = unit >> 4, ksi = unit & 15;
            const float* Wm; float* outp; int Mdim, mb;
            if (mbi < 16){ Wm = Wy; outp = vtp; Mdim = VT; mb = mbi; }
            else         { Wm = WE; outp = ep;  Mdim = ET; mb = mbi - 16; }
            const int lane = tid & 127, bg = tid >> 7;
            const int b0 = bg*8;
            const int m0 = mb*128 + lane;
            const int k0 = ksi*128;
            #pragma unroll
            for (int i = 0; i < 8; ++i){
                int idx = i*TPB + tid; int kk = idx & 127, b = idx >> 7;
                sm.gvtile[kk*36 + b] = flat[b*2048 + k0 + kk];
            }
            __syncthreads();
            bool v0 = m0 < Mdim;
            float acc[8] = {0,0,0,0,0,0,0,0};
            for (int kk = 0; kk < 128; ++kk){
                float4 pq = *(const float4*)&sm.gvtile[kk*36 + b0];
                float4 qq = *(const float4*)&sm.gvtile[kk*36 + b0 + 4];
                float w0 = v0 ? Wm[(size_t)(k0+kk)*Mdim + m0] : 0.f;
                acc[0]+=pq.x*w0; acc[1]+=pq.y*w0; acc[2]+=pq.z*w0; acc[3]+=pq.w*w0;
                acc[4]+=qq.x*w0; acc[5]+=qq.y*w0; acc[6]+=qq.z*w0; acc[7]+=qq.w*w0;
            }
            if (v0){
                #pragma unroll
                for (int bb = 0; bb < 8; ++bb)
                    outp[((size_t)ksi*BSZ + b0+bb)*Mdim + m0] = acc[bb];
            }
            __syncthreads();
        }
        gsync(bar, (++epoch)*NB);
        // ---- phase 6: memory model (blocks 0..31) | vtp presum (blocks 32..159) ----
        if (bid < BSZ){
            const int b = bid;
            float* buf = sm.mm.buf;
            // layernorm of interface vector (1 elem/thread, ET<=512)
            float v = 0.f;
            if (tid < ET){
                #pragma unroll
                for (int s = 0; s < VKS; ++s) v += ep[((size_t)s*BSZ + b)*ET + tid];
            }
            float mean = bsum8(v, sm.mm.wred) * (1.f/ET);
            float dv = (tid < ET) ? (v - mean) : 0.f;
            float var = bsum8(dv*dv, sm.mm.wred) * (1.f/ET);
            float rinv = 1.f / sqrtf(var + 1e-5f);
            if (tid < ET) buf[tid] = dv * rinv;
            __syncthreads();
            if (tid < 64) sm.mm.ers[tid] = sigf(buf[325 + tid]);
            // usage update + sort keys (2 n per thread)
            float f0 = sigf(buf[453]), f1 = sigf(buf[454]), f2 = sigf(buf[455]), f3 = sigf(buf[456]);
            #pragma unroll
            for (int e = 0; e < 2; ++e){
                int n = tid + e*512;
                float4 lw4 = *(const float4*)&lrw[((size_t)b*1024 + n)*4];
                float ret = (1.f - f0*lw4.x)*(1.f - f1*lw4.y)*(1.f - f2*lw4.z)*(1.f - f3*lw4.w);
                float uo = ubuf[b*1024 + n], lwo = lww[b*1024 + n];
                float un = (uo + lwo - uo*lwo) * ret;
                ubuf[b*1024 + n] = un;
                sm.mm.keys[n] = ((ull)__float_as_uint(un) << 32) | (unsigned)n;
            }
            __syncthreads();
            // stable ascending bitonic sort (1024 keys, 2/thread)
            for (int k = 2; k <= 1024; k <<= 1){
                for (int j = k >> 1; j > 0; j >>= 1){
                    #pragma unroll
                    for (int e = 0; e < 2; ++e){
                        int i = tid + e*512;
                        int ixj = i ^ j;
                        if (ixj > i){
                            ull a = sm.mm.keys[i], c = sm.mm.keys[ixj];
                            bool up = ((i & k) == 0);
                            if ((a > c) == up){ sm.mm.keys[i] = c; sm.mm.keys[ixj] = a; }
                        }
                    }
                    __syncthreads();
                }
            }
            float su[2]; int idxv[2];
            #pragma unroll
            for (int e = 0; e < 2; ++e){
                ull kv = sm.mm.keys[tid + e*512];
                su[e] = __uint_as_float((unsigned)(kv >> 32));
                idxv[e] = (int)(kv & 0xffffffffu);
                sm.mm.pa[tid + e*512] = su[e];
            }
            __syncthreads();
            // inclusive scan (product), Hillis-Steele, 2/thread
            float* sA = sm.mm.pa; float* sB = sm.mm.pb;
            for (int off = 1; off < 1024; off <<= 1){
                float v1 = sA[tid];       if (tid >= off) v1 *= sA[tid - off];
                float v2 = sA[tid + 512]; v2 *= sA[tid + 512 - off];
                sB[tid] = v1; sB[tid + 512] = v2;
                __syncthreads();
                float* tmp = sA; sA = sB; sB = tmp;
            }
            #pragma unroll
            for (int e = 0; e < 2; ++e){
                int i = tid + e*512;
                float cp = (i == 0) ? 1.f : sA[i - 1];
                sm.mm.red[idxv[e]] = (1.f - su[e]) * cp;
            }
            __syncthreads();
            float alloc0 = sm.mm.red[tid], alloc1 = sm.mm.red[tid + 512];
            // content write scores (2 rows/thread)
            float ksq = 0.f;
            #pragma unroll 8
            for (int w = 0; w < 64; ++w){ float kk = buf[260 + w]; ksq += kk*kk; }
            float kden = sqrtf(ksq) + 1e-8f;
            float wbeta = 1.f - logsigf(buf[324]);
            float sc[2];
            #pragma unroll 1
            for (int e = 0; e < 2; ++e){
                const float4* Mr4 = (const float4*)(M + ((size_t)b*1024 + tid + e*512)*64);
                float dot = 0.f, msq = 0.f;
                #pragma unroll 4
                for (int i = 0; i < 16; ++i){
                    float4 mv = Mr4[i];
                    int w0 = i*4;
                    dot += mv.x*buf[260+w0] + mv.y*buf[260+w0+1] + mv.z*buf[260+w0+2] + mv.w*buf[260+w0+3];
                    msq += mv.x*mv.x + mv.y*mv.y + mv.z*mv.z + mv.w*mv.w;
                }
                sc[e] = wbeta * dot / ((sqrtf(msq) + 1e-8f) * kden);
            }
            float mx = bmax8(fmaxf(sc[0], sc[1]), sm.mm.wred);
            float ex0 = expf(sc[0]-mx), ex1 = expf(sc[1]-mx);
            float tot = bsum8(ex0 + ex1, sm.mm.wred);
            float ag = sigf(buf[457]), wg = sigf(buf[458]);
            float ww0 = wg*(ag*alloc0 + (1.f-ag)*ex0/tot);
            float ww1 = wg*(ag*alloc1 + (1.f-ag)*ex1/tot);
            lww[b*1024 + tid] = ww0;
            lww[b*1024 + tid + 512] = ww1;
            // memory update + row norms (2 rows/thread)
            float den[2];
            #pragma unroll 1
            for (int e = 0; e < 2; ++e){
                float wwv = e ? ww1 : ww0;
                float4* Mr4 = (float4*)(M + ((size_t)b*1024 + tid + e*512)*64);
                float msq2 = 0.f;
                #pragma unroll 4
                for (int i = 0; i < 16; ++i){
                    float4 mv = Mr4[i];
                    int w0 = i*4;
                    mv.x = mv.x*(1.f - wwv*sm.mm.ers[w0  ]) + wwv*buf[389+w0  ];
                    mv.y = mv.y*(1.f - wwv*sm.mm.ers[w0+1]) + wwv*buf[389+w0+1];
                    mv.z = mv.z*(1.f - wwv*sm.mm.ers[w0+2]) + wwv*buf[389+w0+2];
                    mv.w = mv.w*(1.f - wwv*sm.mm.ers[w0+3]) + wwv*buf[389+w0+3];
                    msq2 += mv.x*mv.x + mv.y*mv.y + mv.z*mv.z + mv.w*mv.w;
                    Mr4[i] = mv;
                }
                den[e] = sqrtf(msq2) + 1e-8f;
            }
            // normalize read keys (buf[0:256], rkeys[w][r] at w*4+r)
            float rb0 = 1.f - logsigf(buf[256]);
            float rb1 = 1.f - logsigf(buf[257]);
            float rb2 = 1.f - logsigf(buf[258]);
            float rb3 = 1.f - logsigf(buf[259]);
            if (tid < 4){
                float s = 0.f;
                #pragma unroll 8
                for (int w = 0; w < 64; ++w){ float q = buf[w*4 + tid]; s += q*q; }
                sm.mm.nrm4[tid] = sqrtf(s) + 1e-8f;
            }
            __syncthreads();
            float scaled = (tid < 256) ? buf[tid] / sm.mm.nrm4[tid & 3] : 0.f;
            __syncthreads();
            if (tid < 256) buf[tid] = scaled;
            __syncthreads();
            // read scores (4 heads x 2 rows)
            float vr[2][4];
            #pragma unroll 1
            for (int e = 0; e < 2; ++e){
                const float4* Mr4 = (const float4*)(M + ((size_t)b*1024 + tid + e*512)*64);
                float d0=0.f, d1=0.f, d2=0.f, d3=0.f;
                #pragma unroll 4
                for (int i = 0; i < 16; ++i){
                    float4 mv = Mr4[i];
                    int w0 = i*4;
                    d0 += mv.x*buf[w0*4+0] + mv.y*buf[(w0+1)*4+0] + mv.z*buf[(w0+2)*4+0] + mv.w*buf[(w0+3)*4+0];
                    d1 += mv.x*buf[w0*4+1] + mv.y*buf[(w0+1)*4+1] + mv.z*buf[(w0+2)*4+1] + mv.w*buf[(w0+3)*4+1];
                    d2 += mv.x*buf[w0*4+2] + mv.y*buf[(w0+1)*4+2] + mv.z*buf[(w0+2)*4+2] + mv.w*buf[(w0+3)*4+2];
                    d3 += mv.x*buf[w0*4+3] + mv.y*buf[(w0+1)*4+3] + mv.z*buf[(w0+2)*4+3] + mv.w*buf[(w0+3)*4+3];
                }
                vr[e][0] = rb0*d0/den[e]; vr[e][1] = rb1*d1/den[e];
                vr[e][2] = rb2*d2/den[e]; vr[e][3] = rb3*d3/den[e];
            }
            // read softmaxes
            float pr[2][4];
            #pragma unroll 1
            for (int r = 0; r < 4; ++r){
                float m2 = bmax8(fmaxf(vr[0][r], vr[1][r]), sm.mm.wred);
                float e0 = expf(vr[0][r]-m2), e1 = expf(vr[1][r]-m2);
                float t2 = bsum8(e0 + e1, sm.mm.wred);
                pr[0][r] = e0/t2; pr[1][r] = e1/t2;
            }
            #pragma unroll
            for (int e = 0; e < 2; ++e){
                int n = tid + e*512;
                float4 pv = make_float4(pr[e][0], pr[e][1], pr[e][2], pr[e][3]);
                *(float4*)&sm.mm.p4[n*4] = pv;
                *(float4*)&lrw[((size_t)b*1024 + n)*4] = pv;
            }
            __syncthreads();
            // read vectors rv[w][r] = sum_n M[n][w]*p[n][r]
            {
                int w = tid & 63, rr = (tid >> 6) & 3, sl = tid >> 8;
                const float* Mb = M + (size_t)b*1024*64;
                float acc = 0.f;
                for (int i = 0; i < 512; ++i){
                    int n2 = sl*512 + i;
                    acc += Mb[(size_t)n2*64 + w] * sm.mm.p4[n2*4 + rr];
                }
                sm.mm.red[tid] = acc;
            }
            __syncthreads();
            if (tid < 256){
                float s = sm.mm.red[tid] + sm.mm.red[tid + 256];
                lrv[b*256 + (tid & 63)*4 + (tid >> 6)] = s;   // [b][w*4+r]
            }
        } else if (bid < 160){
            // vtp partial presum: yt_vt[b*2048+m] = sum_s vtp
            int e = (bid - 32)*TPB + tid;     // e < 65536
            int b = e >> 11, m = e & 2047;
            float acc = 0.f;
            #pragma unroll
            for (int s = 0; s < VKS; ++s) acc += vtp[((size_t)s*BSZ + b)*VT + m];
            yt_vt[e] = acc;
        }
        gsync(bar, (++epoch)*NB);
        // ---- phase 7: ywr + max-over-t (blocks 0..63); overlaps next gemm0 ----
        if (bid < 64){
            #pragma unroll
            for (int i = 0; i < 16; ++i){
                int idx = i*TPB + tid;
                sm.rvf[idx] = lrv[idx];      // [b][256]
            }
            __syncthreads();
            int m = bid*32 + (tid & 31);
            int b0 = (tid >> 5)*2;
            float a0 = 0.f, a1 = 0.f;
            for (int k = 0; k < 256; ++k){
                float wv = Wr[(size_t)k*VT + m];
                a0 += sm.rvf[b0*256 + k]*wv;
                a1 += sm.rvf[(b0+1)*256 + k]*wv;
            }
            float y0 = yt_vt[b0*VT + m] + a0;
            float y1 = yt_vt[(b0+1)*VT + m] + a1;
            if (t == 0){
                out[b0*VT + m] = y0;
                out[(b0+1)*VT + m] = y1;
            } else {
                out[b0*VT + m] = fmaxf(out[b0*VT + m], y0);
                out[(b0+1)*VT + m] = fmaxf(out[(b0+1)*VT + m], y1);
            }
            __syncthreads();
        }
        // no gsync here: next phase-1 only writes gpart and reads xbn/lrv/hstate,
        // all disjoint from phase-7's reads (lrv read-read ok); sync-1 of next
        // step orders everything else.
    }
}

extern "C" void kernel_launch(void* const* d_in, const int* in_sizes, int n_in,
                              void* d_out, int out_size, void* d_ws, size_t ws_size,
                              hipStream_t stream){
    const float* x      = (const float*)d_in[0];
    const float* mem0   = (const float*)d_in[1];
    const float* Wy     = (const float*)d_in[2];
    const float* WE     = (const float*)d_in[3];
    const float* Wr     = (const float*)d_in[4];
    const float* Wih0   = (const float*)d_in[5];
    const float* Whh0   = (const float*)d_in[6];
    const float* bih0   = (const float*)d_in[7];
    const float* bhh0   = (const float*)d_in[8];
    const float* Wih1   = (const float*)d_in[9];
    const float* Whh1   = (const float*)d_in[10];
    const float* bih1   = (const float*)d_in[11];
    const float* bhh1   = (const float*)d_in[12];
    float* out = (float*)d_out;

    unsigned* bar = (unsigned*)d_ws;
    float* p = (float*)d_ws + 16;
    float* hstate = p; p += 4*BSZ*HD;      // zero block start (incl. bar above)
    float* cstate = p; p += 4*BSZ*HD;
    float* ubuf   = p; p += BSZ*NDM;
    float* lww    = p; p += BSZ*NDM;
    float* lrw    = p; p += BSZ*NDM*RDM;
    float* lrv    = p; p += BSZ*256;       // zero block end
    float* M      = p; p += (size_t)BSZ*NDM*WD;
    float* xbn    = p; p += (size_t)TT*BSZ*XD;
    float* lin1   = p; p += BSZ*1024;
    float* gpart  = p; p += (size_t)2*GKS*BSZ*2048;
    float* flat   = p; p += BSZ*2048;
    float* vtp    = p; p += (size_t)VKS*BSZ*VT;
    float* ep     = p; p += (size_t)VKS*BSZ*ET;
    float* yt_vt  = p; p += BSZ*VT;

    size_t zbytes = 64 + ((size_t)(4*BSZ*HD)*2 + BSZ*NDM*2 + BSZ*NDM*RDM + BSZ*256)*sizeof(float);
    (void)hipMemsetAsync(d_ws, 0, zbytes, stream);
    (void)hipMemcpyAsync(M, mem0, (size_t)BSZ*NDM*WD*sizeof(float), hipMemcpyDeviceToDevice, stream);

    dnc_persist<<<NB, TPB, 0, stream>>>(
        x, Wy, WE, Wr, Wih0, Whh0, bih0, bhh0, Wih1, Whh1, bih1, bhh1,
        bar, hstate, cstate, ubuf, lww, lrw, lrv,
        M, xbn, lin1, gpart, flat, vtp, ep, yt_vt, out);
}

// Round 6
// 11890.421 us; speedup vs baseline: 2.9589x; 2.9589x over previous
//
#include <hip/hip_runtime.h>
#include <math.h>

#define BSZ 32
#define TT  32
#define XD  128
#define HD  512
#define VT  2048
#define WD  64
#define RDM 4
#define NDM 1024
#define ET  463
#define GKS 8
#define VKS 16
#define NB  256
#define TPB 512

typedef unsigned long long ull;

__device__ __forceinline__ float sigf(float x){ return 1.f/(1.f+expf(-x)); }
__device__ __forceinline__ float logsigf(float x){
    return (x >= 0.f) ? -log1pf(expf(-x)) : x - log1pf(expf(x));
}

union SMem {
    float getile[64*36];        // lstm gemm staging (9.2KB)
    float gvtile[128*36];       // gemv staging (18.4KB)
    struct {
        float buf[464];
        float ers[64];
        float wred[8];
        float nrm4[4];
        ull   keys[1024];
        float pa[1024];
        float pb[1024];
        float red[1024];
        float p4[4096];
    } mm;                       // ~39KB
    float rvf[32*256];          // ywr staging (32KB)
};

// block reductions over 512 threads (8 waves)
__device__ __forceinline__ float bsum8(float v, float* wred){
    #pragma unroll
    for (int o = 32; o > 0; o >>= 1) v += __shfl_xor(v, o);
    int lane = threadIdx.x & 63, wid = threadIdx.x >> 6;
    if (lane == 0) wred[wid] = v;
    __syncthreads();
    if (wid == 0){
        float s = (lane < 8) ? wred[lane] : 0.f;
        #pragma unroll
        for (int o = 4; o > 0; o >>= 1) s += __shfl_xor(s, o);
        if (lane == 0) wred[0] = s;
    }
    __syncthreads();
    float r = wred[0];
    __syncthreads();
    return r;
}
__device__ __forceinline__ float bmax8(float v, float* wred){
    #pragma unroll
    for (int o = 32; o > 0; o >>= 1) v = fmaxf(v, __shfl_xor(v, o));
    int lane = threadIdx.x & 63, wid = threadIdx.x >> 6;
    if (lane == 0) wred[wid] = v;
    __syncthreads();
    if (wid == 0){
        float s = (lane < 8) ? wred[lane] : -3.4e38f;
        #pragma unroll
        for (int o = 4; o > 0; o >>= 1) s = fmaxf(s, __shfl_xor(s, o));
        if (lane == 0) wred[0] = s;
    }
    __syncthreads();
    float r = wred[0];
    __syncthreads();
    return r;
}

// Device-wide barrier, decoupled arrive/broadcast:
//  - cnt (cacheline A): monotonically counts arrivals (relaxed atomicAdd).
//  - flag (cacheline B, 128B away): last arriver publishes epoch (release store).
//  - pollers: RELAXED loads + s_sleep backoff (no per-poll invalidate),
//    one acquire fence on exit.
__device__ __forceinline__ void gsync(unsigned* cnt, unsigned* flag, unsigned e){
    __syncthreads();
    if (threadIdx.x == 0){
        __threadfence();                                     // release prior writes
        unsigned old = atomicAdd(cnt, 1u);                   // device-scope, relaxed
        if (old + 1u == e*NB){
            __hip_atomic_store(flag, e, __ATOMIC_RELEASE, __HIP_MEMORY_SCOPE_AGENT);
        } else {
            while (__hip_atomic_load(flag, __ATOMIC_RELAXED, __HIP_MEMORY_SCOPE_AGENT) < e)
                __builtin_amdgcn_s_sleep(4);
        }
        __threadfence();                                     // acquire
    }
    __syncthreads();
}

// LSTM gemm phase: 256 blocks = (16 jc, 2 d, 8 ks); 512 thr: 4j x 2b acc
__device__ __forceinline__ void lstm_gemm_phase(
    int bid, int tid, float* tile,
    const float* __restrict__ srcA, int stA, int cA,
    const float* __restrict__ srcB, int stB, int cB,
    const float* __restrict__ hsrc,
    const float* __restrict__ Wih, int Kih,
    const float* __restrict__ Whh,
    float* __restrict__ gpart)
{
    const int jc = bid & 15, d = (bid >> 4) & 1, ks = bid >> 5;
    const int jg = tid & 31, bg = tid >> 5;
    const int j0 = jc*128 + jg*4, b0 = bg*2;
    const int cAB = cA + cB, nct = cAB + 8;
    const int per = (nct + 7) >> 3;
    int c0 = ks*per, c1 = min(nct, c0 + per);
    float acc[4][2] = {{0}};
    for (int c = c0; c < c1; ++c){
        const float* src; int stride, kb; const float* Wb; int Kw, kcol;
        if (c < cA){ src = srcA; stride = stA; kb = c*64; Wb = Wih + (size_t)d*2048*Kih; Kw = Kih; kcol = c*64; }
        else if (c < cAB){ src = srcB; stride = stB; kb = (c - cA)*64; Wb = Wih + (size_t)d*2048*Kih; Kw = Kih; kcol = c*64; }
        else { src = hsrc + d*(BSZ*HD); stride = HD; kb = (c - cAB)*64; Wb = Whh + (size_t)d*2048*HD; Kw = HD; kcol = kb; }
        #pragma unroll
        for (int i = 0; i < 4; ++i){
            int idx = i*TPB + tid; int kk = idx & 63, b = idx >> 6;
            tile[kk*36 + b] = src[b*stride + kb + kk];
        }
        __syncthreads();
        const float* wp0 = Wb + (size_t)(j0+0)*Kw + kcol;
        const float* wp1 = Wb + (size_t)(j0+1)*Kw + kcol;
        const float* wp2 = Wb + (size_t)(j0+2)*Kw + kcol;
        const float* wp3 = Wb + (size_t)(j0+3)*Kw + kcol;
        for (int kk = 0; kk < 64; kk += 4){
            float2 a0 = *(const float2*)&tile[(kk+0)*36 + b0];
            float2 a1 = *(const float2*)&tile[(kk+1)*36 + b0];
            float2 a2 = *(const float2*)&tile[(kk+2)*36 + b0];
            float2 a3 = *(const float2*)&tile[(kk+3)*36 + b0];
            float4 w;
            #define ACC1(JJ, WP) \
                w = *(const float4*)(WP + kk); \
                acc[JJ][0] += a0.x*w.x + a1.x*w.y + a2.x*w.z + a3.x*w.w; \
                acc[JJ][1] += a0.y*w.x + a1.y*w.y + a2.y*w.z + a3.y*w.w;
            ACC1(0, wp0) ACC1(1, wp1) ACC1(2, wp2) ACC1(3, wp3)
            #undef ACC1
        }
        __syncthreads();
    }
    #pragma unroll
    for (int bb = 0; bb < 2; ++bb){
        float4 o = make_float4(acc[0][bb], acc[1][bb], acc[2][bb], acc[3][bb]);
        *(float4*)&gpart[((size_t)(d*GKS + ks)*BSZ + (b0+bb))*2048 + j0] = o;
    }
}

// gates: needs exactly 64 blocks x 512 threads (2 dirs x 32 b x 512 u)
__device__ __forceinline__ void gates_phase(
    int bid, int tid,
    const float* __restrict__ gpart,
    const float* __restrict__ bih, const float* __restrict__ bhh,
    float* __restrict__ cstate, float* __restrict__ hstate,
    float* __restrict__ flat, float* __restrict__ lout, int l)
{
    int idx = bid*TPB + tid;
    int u = idx & 511, b = (idx >> 9) & 31, d = idx >> 14;
    int cell = 2*l + d;
    float g[4];
    #pragma unroll
    for (int xg = 0; xg < 4; ++xg){
        int j = xg*512 + u;
        float s = bih[d*2048 + j] + bhh[d*2048 + j];
        #pragma unroll
        for (int ks = 0; ks < GKS; ++ks)
            s += gpart[((size_t)(d*GKS + ks)*BSZ + b)*2048 + j];
        g[xg] = s;
    }
    float ig = sigf(g[0]), fg = sigf(g[1]), og = sigf(g[3]);
    float gg = tanhf(g[2]);
    int ci = (cell*BSZ + b)*HD + u;
    float c2 = fg*cstate[ci] + ig*gg;
    cstate[ci] = c2;
    float h = og*tanhf(c2);
    hstate[ci] = h;
    flat[b*2048 + cell*HD + u] = h;
    if (lout) lout[b*1024 + d*HD + u] = h;
}

__global__ __launch_bounds__(TPB) void dnc_persist(
    const float* __restrict__ x, const float* __restrict__ Wy,
    const float* __restrict__ WE, const float* __restrict__ Wr,
    const float* __restrict__ Wih0, const float* __restrict__ Whh0,
    const float* __restrict__ bih0, const float* __restrict__ bhh0,
    const float* __restrict__ Wih1, const float* __restrict__ Whh1,
    const float* __restrict__ bih1, const float* __restrict__ bhh1,
    unsigned* bar,
    float* hstate, float* cstate, float* ubuf, float* lww, float* lrw, float* lrv,
    float* M, float* xbn, float* lin1, float* gpart, float* flat,
    float* vtp, float* ep, float* yt_vt, float* out)
{
    const int bid = blockIdx.x, tid = threadIdx.x;
    unsigned* cnt  = bar;        // cacheline A
    unsigned* flag = bar + 32;   // cacheline B (128 bytes away)
    unsigned epoch = 0;
    __shared__ SMem sm;

    // ---- batchnorm for all timesteps ----
    if (bid < TT && tid < XD){
        int t = bid, f = tid;
        float vals[BSZ]; float s = 0.f;
        #pragma unroll
        for (int b = 0; b < BSZ; ++b){ vals[b] = x[(b*TT + t)*XD + f]; s += vals[b]; }
        float mean = s * (1.f/BSZ);
        float ss = 0.f;
        #pragma unroll
        for (int b = 0; b < BSZ; ++b){ float d = vals[b] - mean; ss += d*d; }
        float inv = 1.f / sqrtf(ss*(1.f/BSZ) + 1e-5f);
        #pragma unroll
        for (int b = 0; b < BSZ; ++b) xbn[(t*BSZ + b)*XD + f] = (vals[b] - mean)*inv;
    }
    gsync(cnt, flag, ++epoch);

    for (int t = 0; t < TT; ++t){
        // ---- phase 1: LSTM layer0 gemm ----
        lstm_gemm_phase(bid, tid, sm.getile,
                        xbn + (size_t)t*BSZ*XD, XD, 2, lrv, 256, 4,
                        hstate, Wih0, 384, Whh0, gpart);
        gsync(cnt, flag, ++epoch);
        // ---- phase 2: gates layer0 (blocks 0..63 only!) ----
        if (bid < 64)
            gates_phase(bid, tid, gpart, bih0, bhh0, cstate, hstate, flat, lin1, 0);
        gsync(cnt, flag, ++epoch);
        // ---- phase 3: LSTM layer1 gemm ----
        lstm_gemm_phase(bid, tid, sm.getile,
                        lin1, 1024, 16, nullptr, 0, 0,
                        hstate + 2*BSZ*HD, Wih1, 1024, Whh1, gpart);
        gsync(cnt, flag, ++epoch);
        // ---- phase 4: gates layer1 (blocks 0..63 only!) ----
        if (bid < 64)
            gates_phase(bid, tid, gpart, bih1, bhh1, cstate, hstate, flat, nullptr, 1);
        gsync(cnt, flag, ++epoch);
        // ---- phase 5: gemv (Wy + WE), unit loop over (mbi,ksi) ----
        for (int unit = bid; unit < 20*16; unit += NB){
            int mbi = unit >> 4, ksi = unit & 15;
            const float* Wm; float* outp; int Mdim, mb;
            if (mbi < 16){ Wm = Wy; outp = vtp; Mdim = VT; mb = mbi; }
            else         { Wm = WE; outp = ep;  Mdim = ET; mb = mbi - 16; }
            const int lane = tid & 127, bg = tid >> 7;
            const int b0 = bg*8;
            const int m0 = mb*128 + lane;
            const int k0 = ksi*128;
            #pragma unroll
            for (int i = 0; i < 8; ++i){
                int idx = i*TPB + tid; int kk = idx & 127, b = idx >> 7;
                sm.gvtile[kk*36 + b] = flat[b*2048 + k0 + kk];
            }
            __syncthreads();
            bool v0 = m0 < Mdim;
            float acc[8] = {0,0,0,0,0,0,0,0};
            for (int kk = 0; kk < 128; ++kk){
                float4 pq = *(const float4*)&sm.gvtile[kk*36 + b0];
                float4 qq = *(const float4*)&sm.gvtile[kk*36 + b0 + 4];
                float w0 = v0 ? Wm[(size_t)(k0+kk)*Mdim + m0] : 0.f;
                acc[0]+=pq.x*w0; acc[1]+=pq.y*w0; acc[2]+=pq.z*w0; acc[3]+=pq.w*w0;
                acc[4]+=qq.x*w0; acc[5]+=qq.y*w0; acc[6]+=qq.z*w0; acc[7]+=qq.w*w0;
            }
            if (v0){
                #pragma unroll
                for (int bb = 0; bb < 8; ++bb)
                    outp[((size_t)ksi*BSZ + b0+bb)*Mdim + m0] = acc[bb];
            }
            __syncthreads();
        }
        gsync(cnt, flag, ++epoch);
        // ---- phase 6: memory model (blocks 0..31) | vtp presum (blocks 32..159) ----
        if (bid < BSZ){
            const int b = bid;
            float* buf = sm.mm.buf;
            // layernorm of interface vector (1 elem/thread, ET<=512)
            float v = 0.f;
            if (tid < ET){
                #pragma unroll
                for (int s = 0; s < VKS; ++s) v += ep[((size_t)s*BSZ + b)*ET + tid];
            }
            float mean = bsum8(v, sm.mm.wred) * (1.f/ET);
            float dv = (tid < ET) ? (v - mean) : 0.f;
            float var = bsum8(dv*dv, sm.mm.wred) * (1.f/ET);
            float rinv = 1.f / sqrtf(var + 1e-5f);
            if (tid < ET) buf[tid] = dv * rinv;
            __syncthreads();
            if (tid < 64) sm.mm.ers[tid] = sigf(buf[325 + tid]);
            // usage update + sort keys (2 n per thread)
            float f0 = sigf(buf[453]), f1 = sigf(buf[454]), f2 = sigf(buf[455]), f3 = sigf(buf[456]);
            #pragma unroll
            for (int e = 0; e < 2; ++e){
                int n = tid + e*512;
                float4 lw4 = *(const float4*)&lrw[((size_t)b*1024 + n)*4];
                float ret = (1.f - f0*lw4.x)*(1.f - f1*lw4.y)*(1.f - f2*lw4.z)*(1.f - f3*lw4.w);
                float uo = ubuf[b*1024 + n], lwo = lww[b*1024 + n];
                float un = (uo + lwo - uo*lwo) * ret;
                ubuf[b*1024 + n] = un;
                sm.mm.keys[n] = ((ull)__float_as_uint(un) << 32) | (unsigned)n;
            }
            __syncthreads();
            // stable ascending bitonic sort (1024 keys, 2/thread)
            for (int k = 2; k <= 1024; k <<= 1){
                for (int j = k >> 1; j > 0; j >>= 1){
                    #pragma unroll
                    for (int e = 0; e < 2; ++e){
                        int i = tid + e*512;
                        int ixj = i ^ j;
                        if (ixj > i){
                            ull a = sm.mm.keys[i], c = sm.mm.keys[ixj];
                            bool up = ((i & k) == 0);
                            if ((a > c) == up){ sm.mm.keys[i] = c; sm.mm.keys[ixj] = a; }
                        }
                    }
                    __syncthreads();
                }
            }
            float su[2]; int idxv[2];
            #pragma unroll
            for (int e = 0; e < 2; ++e){
                ull kv = sm.mm.keys[tid + e*512];
                su[e] = __uint_as_float((unsigned)(kv >> 32));
                idxv[e] = (int)(kv & 0xffffffffu);
                sm.mm.pa[tid + e*512] = su[e];
            }
            __syncthreads();
            // inclusive scan (product), Hillis-Steele, 2/thread
            float* sA = sm.mm.pa; float* sB = sm.mm.pb;
            for (int off = 1; off < 1024; off <<= 1){
                float v1 = sA[tid];       if (tid >= off) v1 *= sA[tid - off];
                float v2 = sA[tid + 512]; v2 *= sA[tid + 512 - off];
                sB[tid] = v1; sB[tid + 512] = v2;
                __syncthreads();
                float* tmp = sA; sA = sB; sB = tmp;
            }
            #pragma unroll
            for (int e = 0; e < 2; ++e){
                int i = tid + e*512;
                float cp = (i == 0) ? 1.f : sA[i - 1];
                sm.mm.red[idxv[e]] = (1.f - su[e]) * cp;
            }
            __syncthreads();
            float alloc0 = sm.mm.red[tid], alloc1 = sm.mm.red[tid + 512];
            // content write scores (2 rows/thread)
            float ksq = 0.f;
            #pragma unroll 8
            for (int w = 0; w < 64; ++w){ float kk = buf[260 + w]; ksq += kk*kk; }
            float kden = sqrtf(ksq) + 1e-8f;
            float wbeta = 1.f - logsigf(buf[324]);
            float sc[2];
            #pragma unroll 1
            for (int e = 0; e < 2; ++e){
                const float4* Mr4 = (const float4*)(M + ((size_t)b*1024 + tid + e*512)*64);
                float dot = 0.f, msq = 0.f;
                #pragma unroll 4
                for (int i = 0; i < 16; ++i){
                    float4 mv = Mr4[i];
                    int w0 = i*4;
                    dot += mv.x*buf[260+w0] + mv.y*buf[260+w0+1] + mv.z*buf[260+w0+2] + mv.w*buf[260+w0+3];
                    msq += mv.x*mv.x + mv.y*mv.y + mv.z*mv.z + mv.w*mv.w;
                }
                sc[e] = wbeta * dot / ((sqrtf(msq) + 1e-8f) * kden);
            }
            float mx = bmax8(fmaxf(sc[0], sc[1]), sm.mm.wred);
            float ex0 = expf(sc[0]-mx), ex1 = expf(sc[1]-mx);
            float tot = bsum8(ex0 + ex1, sm.mm.wred);
            float ag = sigf(buf[457]), wg = sigf(buf[458]);
            float ww0 = wg*(ag*alloc0 + (1.f-ag)*ex0/tot);
            float ww1 = wg*(ag*alloc1 + (1.f-ag)*ex1/tot);
            lww[b*1024 + tid] = ww0;
            lww[b*1024 + tid + 512] = ww1;
            // memory update + row norms (2 rows/thread)
            float den[2];
            #pragma unroll 1
            for (int e = 0; e < 2; ++e){
                float wwv = e ? ww1 : ww0;
                float4* Mr4 = (float4*)(M + ((size_t)b*1024 + tid + e*512)*64);
                float msq2 = 0.f;
                #pragma unroll 4
                for (int i = 0; i < 16; ++i){
                    float4 mv = Mr4[i];
                    int w0 = i*4;
                    mv.x = mv.x*(1.f - wwv*sm.mm.ers[w0  ]) + wwv*buf[389+w0  ];
                    mv.y = mv.y*(1.f - wwv*sm.mm.ers[w0+1]) + wwv*buf[389+w0+1];
                    mv.z = mv.z*(1.f - wwv*sm.mm.ers[w0+2]) + wwv*buf[389+w0+2];
                    mv.w = mv.w*(1.f - wwv*sm.mm.ers[w0+3]) + wwv*buf[389+w0+3];
                    msq2 += mv.x*mv.x + mv.y*mv.y + mv.z*mv.z + mv.w*mv.w;
                    Mr4[i] = mv;
                }
                den[e] = sqrtf(msq2) + 1e-8f;
            }
            // normalize read keys (buf[0:256], rkeys[w][r] at w*4+r)
            float rb0 = 1.f - logsigf(buf[256]);
            float rb1 = 1.f - logsigf(buf[257]);
            float rb2 = 1.f - logsigf(buf[258]);
            float rb3 = 1.f - logsigf(buf[259]);
            if (tid < 4){
                float s = 0.f;
                #pragma unroll 8
                for (int w = 0; w < 64; ++w){ float q = buf[w*4 + tid]; s += q*q; }
                sm.mm.nrm4[tid] = sqrtf(s) + 1e-8f;
            }
            __syncthreads();
            float scaled = (tid < 256) ? buf[tid] / sm.mm.nrm4[tid & 3] : 0.f;
            __syncthreads();
            if (tid < 256) buf[tid] = scaled;
            __syncthreads();
            // read scores (4 heads x 2 rows)
            float vr[2][4];
            #pragma unroll 1
            for (int e = 0; e < 2; ++e){
                const float4* Mr4 = (const float4*)(M + ((size_t)b*1024 + tid + e*512)*64);
                float d0=0.f, d1=0.f, d2=0.f, d3=0.f;
                #pragma unroll 4
                for (int i = 0; i < 16; ++i){
                    float4 mv = Mr4[i];
                    int w0 = i*4;
                    d0 += mv.x*buf[w0*4+0] + mv.y*buf[(w0+1)*4+0] + mv.z*buf[(w0+2)*4+0] + mv.w*buf[(w0+3)*4+0];
                    d1 += mv.x*buf[w0*4+1] + mv.y*buf[(w0+1)*4+1] + mv.z*buf[(w0+2)*4+1] + mv.w*buf[(w0+3)*4+1];
                    d2 += mv.x*buf[w0*4+2] + mv.y*buf[(w0+1)*4+2] + mv.z*buf[(w0+2)*4+2] + mv.w*buf[(w0+3)*4+2];
                    d3 += mv.x*buf[w0*4+3] + mv.y*buf[(w0+1)*4+3] + mv.z*buf[(w0+2)*4+3] + mv.w*buf[(w0+3)*4+3];
                }
                vr[e][0] = rb0*d0/den[e]; vr[e][1] = rb1*d1/den[e];
                vr[e][2] = rb2*d2/den[e]; vr[e][3] = rb3*d3/den[e];
            }
            // read softmaxes
            float pr[2][4];
            #pragma unroll 1
            for (int r = 0; r < 4; ++r){
                float m2 = bmax8(fmaxf(vr[0][r], vr[1][r]), sm.mm.wred);
                float e0 = expf(vr[0][r]-m2), e1 = expf(vr[1][r]-m2);
                float t2 = bsum8(e0 + e1, sm.mm.wred);
                pr[0][r] = e0/t2; pr[1][r] = e1/t2;
            }
            #pragma unroll
            for (int e = 0; e < 2; ++e){
                int n = tid + e*512;
                float4 pv = make_float4(pr[e][0], pr[e][1], pr[e][2], pr[e][3]);
                *(float4*)&sm.mm.p4[n*4] = pv;
                *(float4*)&lrw[((size_t)b*1024 + n)*4] = pv;
            }
            __syncthreads();
            // read vectors rv[w][r] = sum_n M[n][w]*p[n][r]
            {
                int w = tid & 63, rr = (tid >> 6) & 3, sl = tid >> 8;
                const float* Mb = M + (size_t)b*1024*64;
                float acc = 0.f;
                for (int i = 0; i < 512; ++i){
                    int n2 = sl*512 + i;
                    acc += Mb[(size_t)n2*64 + w] * sm.mm.p4[n2*4 + rr];
                }
                sm.mm.red[tid] = acc;
            }
            __syncthreads();
            if (tid < 256){
                float s = sm.mm.red[tid] + sm.mm.red[tid + 256];
                lrv[b*256 + (tid & 63)*4 + (tid >> 6)] = s;   // [b][w*4+r]
            }
        } else if (bid < 160){
            // vtp partial presum: yt_vt[b*2048+m] = sum_s vtp
            int e = (bid - 32)*TPB + tid;     // e < 65536
            int b = e >> 11, m = e & 2047;
            float acc = 0.f;
            #pragma unroll
            for (int s = 0; s < VKS; ++s) acc += vtp[((size_t)s*BSZ + b)*VT + m];
            yt_vt[e] = acc;
        }
        gsync(cnt, flag, ++epoch);
        // ---- phase 7: ywr + max-over-t (blocks 0..63); overlaps next gemm0 ----
        if (bid < 64){
            #pragma unroll
            for (int i = 0; i < 16; ++i){
                int idx = i*TPB + tid;
                sm.rvf[idx] = lrv[idx];      // [b][256]
            }
            __syncthreads();
            int m = bid*32 + (tid & 31);
            int b0 = (tid >> 5)*2;
            float a0 = 0.f, a1 = 0.f;
            for (int k = 0; k < 256; ++k){
                float wv = Wr[(size_t)k*VT + m];
                a0 += sm.rvf[b0*256 + k]*wv;
                a1 += sm.rvf[(b0+1)*256 + k]*wv;
            }
            float y0 = yt_vt[b0*VT + m] + a0;
            float y1 = yt_vt[(b0+1)*VT + m] + a1;
            if (t == 0){
                out[b0*VT + m] = y0;
                out[(b0+1)*VT + m] = y1;
            } else {
                out[b0*VT + m] = fmaxf(out[b0*VT + m], y0);
                out[(b0+1)*VT + m] = fmaxf(out[(b0+1)*VT + m], y1);
            }
            __syncthreads();
        }
        // no gsync here: next phase-1 only writes gpart and reads xbn/lrv/hstate,
        // all disjoint from phase-7's reads (lrv read-read ok); sync-1 of next
        // step orders everything else.
    }
}

extern "C" void kernel_launch(void* const* d_in, const int* in_sizes, int n_in,
                              void* d_out, int out_size, void* d_ws, size_t ws_size,
                              hipStream_t stream){
    const float* x      = (const float*)d_in[0];
    const float* mem0   = (const float*)d_in[1];
    const float* Wy     = (const float*)d_in[2];
    const float* WE     = (const float*)d_in[3];
    const float* Wr     = (const float*)d_in[4];
    const float* Wih0   = (const float*)d_in[5];
    const float* Whh0   = (const float*)d_in[6];
    const float* bih0   = (const float*)d_in[7];
    const float* bhh0   = (const float*)d_in[8];
    const float* Wih1   = (const float*)d_in[9];
    const float* Whh1   = (const float*)d_in[10];
    const float* bih1   = (const float*)d_in[11];
    const float* bhh1   = (const float*)d_in[12];
    float* out = (float*)d_out;

    unsigned* bar = (unsigned*)d_ws;       // cnt at [0], flag at [32] (128B apart)
    float* p = (float*)d_ws + 64;          // 256B reserved for barrier lines
    float* hstate = p; p += 4*BSZ*HD;      // zero block start
    float* cstate = p; p += 4*BSZ*HD;
    float* ubuf   = p; p += BSZ*NDM;
    float* lww    = p; p += BSZ*NDM;
    float* lrw    = p; p += BSZ*NDM*RDM;
    float* lrv    = p; p += BSZ*256;       // zero block end
    float* M      = p; p += (size_t)BSZ*NDM*WD;
    float* xbn    = p; p += (size_t)TT*BSZ*XD;
    float* lin1   = p; p += BSZ*1024;
    float* gpart  = p; p += (size_t)2*GKS*BSZ*2048;
    float* flat   = p; p += BSZ*2048;
    float* vtp    = p; p += (size_t)VKS*BSZ*VT;
    float* ep     = p; p += (size_t)VKS*BSZ*ET;
    float* yt_vt  = p; p += BSZ*VT;

    size_t zbytes = 256 + ((size_t)(4*BSZ*HD)*2 + BSZ*NDM*2 + BSZ*NDM*RDM + BSZ*256)*sizeof(float);
    (void)hipMemsetAsync(d_ws, 0, zbytes, stream);
    (void)hipMemcpyAsync(M, mem0, (size_t)BSZ*NDM*WD*sizeof(float), hipMemcpyDeviceToDevice, stream);

    dnc_persist<<<NB, TPB, 0, stream>>>(
        x, Wy, WE, Wr, Wih0, Whh0, bih0, bhh0, Wih1, Whh1, bih1, bhh1,
        bar, hstate, cstate, ubuf, lww, lrw, lrv,
        M, xbn, lin1, gpart, flat, vtp, ep, yt_vt, out);
}